// Round 1
// 8331.525 us; speedup vs baseline: 2.2895x; 2.2895x over previous
//
#include <hip/hip_runtime.h>

#define NB 8
#define T 32000
#define NLAYERS 30
#define RES 64
#define GATE 128
#define SKIPC 64
#define CIN 80
#define OUTC 256
#define TF 400
#define TM 4000

// ---- packed bf16 split-weight layout (u16 units, per layer) ----
// gate A: [wave 0..3][kc 0..12][lane 0..63][e 0..7]  (hi then lo)
// A2    : [wave 0..3][kc 0..3 ][lane 0..63][e 0..7]  (hi then lo)
#define K1 208          // 64 tap0 + 64 tap1 + 80 cond
#define AHI_SZ 26624    // 128*208
#define A2SZ   8192     // 128*64
#define A2_OFF (2*AHI_SZ)
#define L_U16  (2*AHI_SZ + 2*A2SZ)   // 69632 u16 per layer

typedef __bf16 bf16x8 __attribute__((ext_vector_type(8)));
typedef float  f32x16 __attribute__((ext_vector_type(16)));

__device__ __forceinline__ unsigned short bf16_rtne(float x) {
    unsigned u = __float_as_uint(x);
    u += 0x7fffu + ((u >> 16) & 1u);
    return (unsigned short)(u >> 16);
}
__device__ __forceinline__ float bf16_f(unsigned short h) {
    return __uint_as_float(((unsigned)h) << 16);
}
__device__ __forceinline__ unsigned split_pack(float x) {
    unsigned short hi = bf16_rtne(x);
    unsigned short lo = bf16_rtne(x - bf16_f(hi));
    return (unsigned)hi | ((unsigned)lo << 16);
}

// Pack weights: split each fp32 weight into bf16 hi/lo, permute gate rows so
// packed row 2o = tanh-row o, 2o+1 = sigmoid-row (o+64), and lay out in
// per-wave MFMA fragment order. Also emit transposed last1 (fp32).
__global__ void pack_weights(const float* __restrict__ conv_w,
                             const float* __restrict__ cond_w,
                             const float* __restrict__ skip_w,
                             const float* __restrict__ out_w,
                             const float* __restrict__ last1_w,
                             unsigned short* __restrict__ wp16,
                             float* __restrict__ l1t) {
    int e = blockIdx.x * 256 + threadIdx.x;
    const int NW = NLAYERS * 34816;          // 34816 = 128*208 + 128*64 elements/layer
    if (e < NW) {
        int l = e / 34816, r = e % 34816;
        float wv;
        int dst, losz;
        if (r < 26624) {                     // gate A
            int pr = r / K1, k = r % K1;
            int o = (pr & 1) * 64 + (pr >> 1);   // original gate row
            if (k < 64)       wv = conv_w[((l*GATE + o)*RES + k)*2 + 0];
            else if (k < 128) wv = conv_w[((l*GATE + o)*RES + (k-64))*2 + 1];
            else              wv = cond_w[(l*GATE + o)*CIN + (k-128)];
            int w = pr >> 5, r31 = pr & 31, kc = k >> 4, lg = (k >> 3) & 1, ee = k & 7;
            dst = l*L_U16 + ((w*13 + kc)*64 + lg*32 + r31)*8 + ee;
            losz = AHI_SZ;
        } else {                             // A2: skip rows 0-63, res rows 64-127
            int r2 = r - 26624;
            int row = r2 >> 6, k = r2 & 63;
            wv = (row < 64) ? skip_w[(l*64 + row)*64 + k]
                            : out_w[(l*64 + (row-64))*64 + k];
            int w = row >> 5, r31 = row & 31, kc = k >> 4, lg = (k >> 3) & 1, ee = k & 7;
            dst = l*L_U16 + A2_OFF + ((w*4 + kc)*64 + lg*32 + r31)*8 + ee;
            losz = A2SZ;
        }
        unsigned short hi = bf16_rtne(wv);
        wp16[dst] = hi;
        wp16[dst + losz] = bf16_rtne(wv - bf16_f(hi));
    } else if (e < NW + 4096) {
        int r = e - NW;
        int i = r >> 6, o = r & 63;
        l1t[r] = last1_w[o * 64 + i];        // transposed [i][o]
    }
}

// h[b,o,t] = split_pack(first_w[o, x[b,t]] + first_b[o])
__global__ void first_conv(const int* __restrict__ x, const float* __restrict__ fw,
                           const float* __restrict__ fb, unsigned* __restrict__ h) {
    int tid = blockIdx.x * 256 + threadIdx.x;
    int b = tid / T, t = tid - b * T;
    int idx = x[tid];
    int base = (b * RES) * T + t;
    for (int o = 0; o < RES; ++o)
        h[base + o * T] = split_pack(fw[o * OUTC + idx] + fb[o]);
}

__global__ void cond_in(const float* __restrict__ cond, const float* __restrict__ cw,
                        float* __restrict__ c1) {
    int tid = blockIdx.x * blockDim.x + threadIdx.x;
    if (tid >= NB * TF) return;
    int b = tid / TF, t = tid - b * TF;
    float in[CIN];
#pragma unroll
    for (int i = 0; i < CIN; ++i) in[i] = cond[(b * CIN + i) * TF + t];
    for (int o = 0; o < CIN; ++o) {
        float acc = 0.f;
#pragma unroll
        for (int i = 0; i < CIN; ++i) acc += cw[o * CIN + i] * in[i];
        c1[(b * CIN + o) * TF + t] = acc;
    }
}

__global__ void up1(const float* __restrict__ src, float* __restrict__ dst) {
    int tid = blockIdx.x * 256 + threadIdx.x;
    int t = tid % TM, rc = tid / TM;
    const float* s = src + rc * TF;
    float acc = 0.f;
#pragma unroll
    for (int k = -10; k <= 10; ++k) {
        int j = t + k;
        if (j >= 0 && j < TM) acc += s[j / 10];
    }
    dst[tid] = acc * (1.f / 21.f);
}

__global__ void up2(const float* __restrict__ src, unsigned* __restrict__ dst) {
    int tid = blockIdx.x * 256 + threadIdx.x;
    int t = tid % T, rc = tid / T;
    const float* s = src + rc * TM;
    float acc = 0.f;
#pragma unroll
    for (int k = -8; k <= 8; ++k) {
        int j = t + k;
        if (j >= 0 && j < T) acc += s[j >> 3];
    }
    dst[tid] = split_pack(acc * (1.f / 17.f));
}

// Fused WaveNet layer on matrix cores. One block = one (b, 64-wide t-tile).
// h/c are stored pre-split as u32 = bf16hi | bf16lo<<16.
__global__ __launch_bounds__(256, 2)
void layer_k(const unsigned* __restrict__ h_in, unsigned* __restrict__ h_out,
             float* __restrict__ skips, const unsigned* __restrict__ c,
             const unsigned short* __restrict__ wp16,
             const float* __restrict__ conv_b, const float* __restrict__ skip_b,
             const float* __restrict__ out_b,
             int l, int d, int first) {
    // fragment-order LDS: [kc][nt][lane][8 u16]
    __shared__ __align__(16) unsigned short Bh[13*2*64*8];
    __shared__ __align__(16) unsigned short Bl[13*2*64*8];
    __shared__ __align__(16) unsigned short Zh[4*2*64*8];
    __shared__ __align__(16) unsigned short Zl[4*2*64*8];

    int tid = threadIdx.x;
    int blk = blockIdx.x;
    int b = blk / (T/64);
    int t0 = (blk % (T/64)) * 64;
    int w = tid >> 6, lane = tid & 63;
    int l31 = lane & 31, lg = lane >> 5;

    // ---- stage B = [Hd(64) | H(64) | C(80)] rows x 64 cols, split hi/lo ----
    {
        int col = lane;                   // wave w stages k in [52w, 52w+52)
        int tcol = t0 + col;
        const unsigned* hb = h_in + b * (RES * T);
        const unsigned* cb = c + b * (CIN * T);
        unsigned short* Bh16 = Bh;
        unsigned short* Bl16 = Bl;
        for (int kk = 0; kk < 52; kk += 4) {
            int k = w * 52 + kk;
            unsigned v0, v1, v2, v3;
            if (k < 64) {
                int ts = tcol - d;
                bool ok = ts >= 0;
                v0 = ok ? hb[(k+0)*T + ts] : 0u;
                v1 = ok ? hb[(k+1)*T + ts] : 0u;
                v2 = ok ? hb[(k+2)*T + ts] : 0u;
                v3 = ok ? hb[(k+3)*T + ts] : 0u;
            } else if (k < 128) {
                v0 = hb[(k-64)*T + tcol];
                v1 = hb[(k-63)*T + tcol];
                v2 = hb[(k-62)*T + tcol];
                v3 = hb[(k-61)*T + tcol];
            } else {
                v0 = cb[(k-128)*T + tcol];
                v1 = cb[(k-127)*T + tcol];
                v2 = cb[(k-126)*T + tcol];
                v3 = cb[(k-125)*T + tcol];
            }
            uint2 whi = make_uint2((v0 & 0xffffu) | (v1 << 16),
                                   (v2 & 0xffffu) | (v3 << 16));
            uint2 wlo = make_uint2((v0 >> 16) | (v1 & 0xffff0000u),
                                   (v2 >> 16) | (v3 & 0xffff0000u));
            int off = ((k >> 4)*2 + (col >> 5))*512 + ((col & 31) + (((k >> 3) & 1) << 5))*8 + (k & 7);
            *(uint2*)(Bh16 + off) = whi;
            *(uint2*)(Bl16 + off) = wlo;
        }
    }
    __syncthreads();

    const unsigned short* wA = wp16 + l * L_U16;

    // ---- gate GEMM: 128 packed rows x 64 cols, K=208, 3-product bf16 split ----
    f32x16 acc0, acc1;
#pragma unroll
    for (int i = 0; i < 16; ++i) { acc0[i] = 0.f; acc1[i] = 0.f; }

    const bf16x8* BhF = (const bf16x8*)Bh;
    const bf16x8* BlF = (const bf16x8*)Bl;
    const unsigned short* aG = wA + (w*13*64 + lane)*8;
#pragma unroll
    for (int kc = 0; kc < 13; ++kc) {
        bf16x8 ah = *(const bf16x8*)(aG + kc*512);
        bf16x8 al = *(const bf16x8*)(aG + AHI_SZ + kc*512);
        bf16x8 bh0 = BhF[(kc*2 + 0)*64 + lane];
        bf16x8 bh1 = BhF[(kc*2 + 1)*64 + lane];
        bf16x8 bl0 = BlF[(kc*2 + 0)*64 + lane];
        bf16x8 bl1 = BlF[(kc*2 + 1)*64 + lane];
        acc0 = __builtin_amdgcn_mfma_f32_32x32x16_bf16(ah, bh0, acc0, 0, 0, 0);
        acc1 = __builtin_amdgcn_mfma_f32_32x32x16_bf16(ah, bh1, acc1, 0, 0, 0);
        acc0 = __builtin_amdgcn_mfma_f32_32x32x16_bf16(ah, bl0, acc0, 0, 0, 0);
        acc1 = __builtin_amdgcn_mfma_f32_32x32x16_bf16(ah, bl1, acc1, 0, 0, 0);
        acc0 = __builtin_amdgcn_mfma_f32_32x32x16_bf16(al, bh0, acc0, 0, 0, 0);
        acc1 = __builtin_amdgcn_mfma_f32_32x32x16_bf16(al, bh1, acc1, 0, 0, 0);
    }

    // ---- gating: pair (reg 2q, 2q+1) = (a,b) rows of z-row 16w+jl, in-lane ----
    {
        const float* cbl = conv_b + l * GATE;
        unsigned* Zh32 = (unsigned*)Zh;
        unsigned* Zl32 = (unsigned*)Zl;
#pragma unroll
        for (int nt = 0; nt < 2; ++nt) {
            const f32x16& A = nt ? acc1 : acc0;
#pragma unroll
            for (int q = 0; q < 8; q += 2) {
                float z2[2];
#pragma unroll
                for (int s = 0; s < 2; ++s) {
                    int qq = q + s;
                    int jl = 4*(qq >> 1) + 2*lg + (qq & 1);
                    int zr = 16*w + jl;
                    float a  = A[2*qq]     + cbl[zr];
                    float bb = A[2*qq + 1] + cbl[64 + zr];
                    a  = fminf(fmaxf(a, -15.f), 15.f);
                    bb = fminf(fmaxf(bb, -30.f), 30.f);
                    float e2 = __expf(2.f * a);
                    float th = (e2 - 1.f) / (e2 + 1.f);
                    float sg = 1.f / (1.f + __expf(-bb));
                    z2[s] = th * sg;
                }
                unsigned short h0 = bf16_rtne(z2[0]);
                unsigned short h1 = bf16_rtne(z2[1]);
                unsigned short o0 = bf16_rtne(z2[0] - bf16_f(h0));
                unsigned short o1 = bf16_rtne(z2[1] - bf16_f(h1));
                int jl0 = 4*(q >> 1) + 2*lg;
                int zr = 16*w + jl0;
                int off = ((zr >> 4)*2 + nt)*512 + (l31 + (((zr >> 3) & 1) << 5))*8 + (zr & 7);
                Zh32[off >> 1] = (unsigned)h0 | ((unsigned)h1 << 16);
                Zl32[off >> 1] = (unsigned)o0 | ((unsigned)o1 << 16);
            }
        }
    }
    __syncthreads();

    // ---- second GEMM: [skip(64)|res(64)] rows x 64 cols, K=64 over z ----
    f32x16 s0, s1;
#pragma unroll
    for (int i = 0; i < 16; ++i) { s0[i] = 0.f; s1[i] = 0.f; }
    {
        const bf16x8* ZhF = (const bf16x8*)Zh;
        const bf16x8* ZlF = (const bf16x8*)Zl;
        const unsigned short* aG2 = wA + A2_OFF + (w*4*64 + lane)*8;
#pragma unroll
        for (int kc = 0; kc < 4; ++kc) {
            bf16x8 ah = *(const bf16x8*)(aG2 + kc*512);
            bf16x8 al = *(const bf16x8*)(aG2 + A2SZ + kc*512);
            bf16x8 bh0 = ZhF[(kc*2 + 0)*64 + lane];
            bf16x8 bh1 = ZhF[(kc*2 + 1)*64 + lane];
            bf16x8 bl0 = ZlF[(kc*2 + 0)*64 + lane];
            bf16x8 bl1 = ZlF[(kc*2 + 1)*64 + lane];
            s0 = __builtin_amdgcn_mfma_f32_32x32x16_bf16(ah, bh0, s0, 0, 0, 0);
            s1 = __builtin_amdgcn_mfma_f32_32x32x16_bf16(ah, bh1, s1, 0, 0, 0);
            s0 = __builtin_amdgcn_mfma_f32_32x32x16_bf16(ah, bl0, s0, 0, 0, 0);
            s1 = __builtin_amdgcn_mfma_f32_32x32x16_bf16(ah, bl1, s1, 0, 0, 0);
            s0 = __builtin_amdgcn_mfma_f32_32x32x16_bf16(al, bh0, s0, 0, 0, 0);
            s1 = __builtin_amdgcn_mfma_f32_32x32x16_bf16(al, bh1, s1, 0, 0, 0);
        }
    }

    // ---- epilogue: waves 0,1 -> skips (fp32 accumulate); waves 2,3 -> h_out ----
    int tcol0 = t0 + l31;
    if (w < 2) {
        float* sp = skips + (b * SKIPC) * T + tcol0;
        const float* sbl = skip_b + l * SKIPC;
#pragma unroll
        for (int nt = 0; nt < 2; ++nt) {
            const f32x16& S = nt ? s1 : s0;
#pragma unroll
            for (int reg = 0; reg < 16; ++reg) {
                int row = 32*w + (reg & 3) + 8*(reg >> 2) + 4*lg;
                int idx = row * T + nt*32;
                float v = S[reg] + sbl[row];
                if (!first) v += sp[idx];
                sp[idx] = v;
            }
        }
    } else {
        unsigned* ho = h_out + b * (RES * T) + tcol0;
        const unsigned* hp = h_in + b * (RES * T) + tcol0;
        const float* obl = out_b + l * RES;
#pragma unroll
        for (int nt = 0; nt < 2; ++nt) {
            const f32x16& S = nt ? s1 : s0;
#pragma unroll
            for (int reg = 0; reg < 16; ++reg) {
                int row = 32*(w - 2) + (reg & 3) + 8*(reg >> 2) + 4*lg;
                int idx = row * T + nt*32;
                unsigned hv = hp[idx];
                float hf = bf16_f((unsigned short)(hv & 0xffffu)) +
                           bf16_f((unsigned short)(hv >> 16));
                ho[idx] = split_pack(hf + S[reg] + obl[row]);
            }
        }
    }
}

__global__ __launch_bounds__(256, 2)
void final_k(const float* __restrict__ skips, const float* __restrict__ l1T,
             const float* __restrict__ b1, const float* __restrict__ l2w,
             const float* __restrict__ b2, float* __restrict__ out) {
    int tid = blockIdx.x * 256 + threadIdx.x;
    int b = tid / T, t = tid - b * T;
    int sbase = (b * SKIPC) * T + t;
    float y1[64];
#pragma unroll
    for (int o = 0; o < 64; ++o) y1[o] = b1[o];
    for (int i = 0; i < 64; ++i) {
        float s = fmaxf(skips[sbase + i * T], 0.f);
        const float* w = l1T + i * 64;
#pragma unroll
        for (int o = 0; o < 64; ++o) y1[o] += w[o] * s;
    }
#pragma unroll
    for (int o = 0; o < 64; ++o) y1[o] = fmaxf(y1[o], 0.f);
    int obase = (b * OUTC) * T + t;
    for (int o2 = 0; o2 < OUTC; ++o2) {
        const float* w = l2w + o2 * 64;
        float acc = b2[o2];
#pragma unroll
        for (int i = 0; i < 64; ++i) acc += w[i] * y1[i];
        out[obase + o2 * T] = acc;
    }
}

extern "C" void kernel_launch(void* const* d_in, const int* in_sizes, int n_in,
                              void* d_out, int out_size, void* d_ws, size_t ws_size,
                              hipStream_t stream) {
    const int*   x       = (const int*)  d_in[0];
    const float* cond    = (const float*)d_in[1];
    const float* first_w = (const float*)d_in[2];
    const float* first_b = (const float*)d_in[3];
    const float* cin_w   = (const float*)d_in[4];
    const float* conv_w  = (const float*)d_in[5];
    const float* conv_b  = (const float*)d_in[6];
    const float* cond_w  = (const float*)d_in[7];
    const float* skip_w  = (const float*)d_in[8];
    const float* skip_b  = (const float*)d_in[9];
    const float* out_w   = (const float*)d_in[10];
    const float* out_b   = (const float*)d_in[11];
    const float* last1_w = (const float*)d_in[12];
    const float* last1_b = (const float*)d_in[13];
    const float* last2_w = (const float*)d_in[14];
    const float* last2_b = (const float*)d_in[15];
    float* out = (float*)d_out;

    // ws layout: l1t fp32[4096] | wp16 u16[30*69632] | skips fp32 | c u32  (~152 MB)
    float* ws = (float*)d_ws;
    float* l1t = ws;
    unsigned short* wp16 = (unsigned short*)(ws + 4096);
    float* skips = ws + 4096 + (NLAYERS * L_U16) / 2;
    unsigned* c = (unsigned*)(skips + NB * SKIPC * T);

    // h double-buffer + cond temporaries live inside d_out (final_k overwrites all)
    unsigned* hA = (unsigned*)out;
    unsigned* hB = hA + NB * RES * T;
    float* c2 = (float*)(hB + NB * RES * T);
    float* c1 = c2 + NB * CIN * TM;

    pack_weights<<<4096, 256, 0, stream>>>(conv_w, cond_w, skip_w, out_w, last1_w, wp16, l1t);
    first_conv<<<(NB * T) / 256, 256, 0, stream>>>(x, first_w, first_b, hA);
    cond_in<<<(NB * TF + 255) / 256, 256, 0, stream>>>(cond, cin_w, c1);
    up1<<<(NB * CIN * TM) / 256, 256, 0, stream>>>(c1, c2);
    up2<<<(NB * CIN * T) / 256, 256, 0, stream>>>(c2, c);

    for (int l = 0; l < NLAYERS; ++l) {
        int d = 1 << (l % 10);
        const unsigned* h_in = (l & 1) ? hB : hA;
        unsigned*       h_out = (l & 1) ? hA : hB;
        layer_k<<<NB * (T / 64), 256, 0, stream>>>(h_in, h_out, skips, c, wp16,
                                                   conv_b, skip_b, out_b,
                                                   l, d, (l == 0) ? 1 : 0);
    }
    final_k<<<(NB * T) / 256, 256, 0, stream>>>(skips, l1t, last1_b, last2_w, last2_b, out);
}

// Round 4
// 6242.918 us; speedup vs baseline: 3.0554x; 1.3346x over previous
//
#include <hip/hip_runtime.h>

#define NB 8
#define T 32000
#define NLAYERS 30
#define RES 64
#define GATE 128
#define SKIPC 64
#define CIN 80
#define OUTC 256
#define TF 400
#define TM 4000

// ---- packed bf16 split-weight layout (u16 units, per layer) ----
#define K1 208          // 64 tap0 + 64 tap1 + 80 cond
#define AHI_SZ 26624    // 128*208
#define A2SZ   8192     // 128*64
#define A2_OFF (2*AHI_SZ)
#define L_U16  (2*AHI_SZ + 2*A2SZ)   // 69632 u16 per layer

typedef __bf16 bf16x8 __attribute__((ext_vector_type(8)));
typedef float  f32x16 __attribute__((ext_vector_type(16)));

__device__ __forceinline__ unsigned short bf16_rtne(float x) {
    unsigned u = __float_as_uint(x);
    u += 0x7fffu + ((u >> 16) & 1u);
    return (unsigned short)(u >> 16);
}
__device__ __forceinline__ float bf16_f(unsigned short h) {
    return __uint_as_float(((unsigned)h) << 16);
}
__device__ __forceinline__ unsigned split_pack(float x) {
    unsigned short hi = bf16_rtne(x);
    unsigned short lo = bf16_rtne(x - bf16_f(hi));
    return (unsigned)hi | ((unsigned)lo << 16);
}

// Pack weights (round-1 verified version): split fp32 into bf16 hi/lo, permute
// gate rows (2o = tanh-row o, 2o+1 = sigmoid-row o+64), per-wave MFMA fragment
// order. Also emits transposed last1 (fp32) for the VALU final stage.
__global__ void pack_weights(const float* __restrict__ conv_w,
                             const float* __restrict__ cond_w,
                             const float* __restrict__ skip_w,
                             const float* __restrict__ out_w,
                             const float* __restrict__ last1_w,
                             unsigned short* __restrict__ wp16,
                             float* __restrict__ l1t) {
    int e = blockIdx.x * 256 + threadIdx.x;
    const int NW = NLAYERS * 34816;          // 34816 = 128*208 + 128*64 elements/layer
    if (e < NW) {
        int l = e / 34816, r = e % 34816;
        float wv;
        int dst, losz;
        if (r < 26624) {                     // gate A
            int pr = r / K1, k = r % K1;
            int o = (pr & 1) * 64 + (pr >> 1);   // original gate row
            if (k < 64)       wv = conv_w[((l*GATE + o)*RES + k)*2 + 0];
            else if (k < 128) wv = conv_w[((l*GATE + o)*RES + (k-64))*2 + 1];
            else              wv = cond_w[(l*GATE + o)*CIN + (k-128)];
            int w = pr >> 5, r31 = pr & 31, kc = k >> 4, lg2 = (k >> 3) & 1, ee = k & 7;
            dst = l*L_U16 + ((w*13 + kc)*64 + lg2*32 + r31)*8 + ee;
            losz = AHI_SZ;
        } else {                             // A2: skip rows 0-63, res rows 64-127
            int r2 = r - 26624;
            int row = r2 >> 6, k = r2 & 63;
            wv = (row < 64) ? skip_w[(l*64 + row)*64 + k]
                            : out_w[(l*64 + (row-64))*64 + k];
            int w = row >> 5, r31 = row & 31, kc = k >> 4, lg2 = (k >> 3) & 1, ee = k & 7;
            dst = l*L_U16 + A2_OFF + ((w*4 + kc)*64 + lg2*32 + r31)*8 + ee;
            losz = A2SZ;
        }
        unsigned short hi = bf16_rtne(wv);
        wp16[dst] = hi;
        wp16[dst + losz] = bf16_rtne(wv - bf16_f(hi));
    } else if (e < NW + 4096) {
        int r = e - NW;
        int i = r >> 6, o = r & 63;
        l1t[r] = last1_w[o * 64 + i];        // transposed [i][o]
    }
}

// h[b,o,t] = split_pack(first_w[o, x[b,t]] + first_b[o])
__global__ void first_conv(const int* __restrict__ x, const float* __restrict__ fw,
                           const float* __restrict__ fb, unsigned* __restrict__ h) {
    int tid = blockIdx.x * 256 + threadIdx.x;
    int b = tid / T, t = tid - b * T;
    int idx = x[tid];
    int base = (b * RES) * T + t;
    for (int o = 0; o < RES; ++o)
        h[base + o * T] = split_pack(fw[o * OUTC + idx] + fb[o]);
}

__global__ void cond_in(const float* __restrict__ cond, const float* __restrict__ cw,
                        float* __restrict__ c1) {
    int tid = blockIdx.x * blockDim.x + threadIdx.x;
    if (tid >= NB * TF) return;
    int b = tid / TF, t = tid - b * TF;
    float in[CIN];
#pragma unroll
    for (int i = 0; i < CIN; ++i) in[i] = cond[(b * CIN + i) * TF + t];
    for (int o = 0; o < CIN; ++o) {
        float acc = 0.f;
#pragma unroll
        for (int i = 0; i < CIN; ++i) acc += cw[o * CIN + i] * in[i];
        c1[(b * CIN + o) * TF + t] = acc;
    }
}

__global__ void up1(const float* __restrict__ src, float* __restrict__ dst) {
    int tid = blockIdx.x * 256 + threadIdx.x;
    int t = tid % TM, rc = tid / TM;
    const float* s = src + rc * TF;
    float acc = 0.f;
#pragma unroll
    for (int k = -10; k <= 10; ++k) {
        int j = t + k;
        if (j >= 0 && j < TM) acc += s[j / 10];
    }
    dst[tid] = acc * (1.f / 21.f);
}

__global__ void up2(const float* __restrict__ src, unsigned* __restrict__ dst) {
    int tid = blockIdx.x * 256 + threadIdx.x;
    int t = tid % T, rc = tid / T;
    const float* s = src + rc * TM;
    float acc = 0.f;
#pragma unroll
    for (int k = -8; k <= 8; ++k) {
        int j = t + k;
        if (j >= 0 && j < T) acc += s[j >> 3];
    }
    dst[tid] = split_pack(acc * (1.f / 17.f));
}

// Fused WaveNet layer on matrix cores. One block = one (b, 64-wide t-tile).
// 8 waves: wave = (wr, wc); wr = 32-row group (0..3), wc = 32-col tile (0..1).
// Same math/layout/barriers as the round-1 verified 4-wave version; only the
// wave->tile assignment changed (1 MFMA tile per wave) for 2x occupancy.
__global__ __launch_bounds__(512, 4)
void layer_k(const unsigned* __restrict__ h_in, unsigned* __restrict__ h_out,
             float* __restrict__ skips, const unsigned* __restrict__ c,
             const unsigned short* __restrict__ wp16,
             const float* __restrict__ conv_b, const float* __restrict__ skip_b,
             const float* __restrict__ out_b,
             int l, int d, int first) {
    // fragment-order LDS: [kc][nt][lane][8 u16]
    __shared__ __align__(16) unsigned short Bh[13*2*64*8];
    __shared__ __align__(16) unsigned short Bl[13*2*64*8];
    __shared__ __align__(16) unsigned short Zh[4*2*64*8];
    __shared__ __align__(16) unsigned short Zl[4*2*64*8];

    int tid = threadIdx.x;
    int blk = blockIdx.x;
    int b = blk / (T/64);
    int t0 = (blk % (T/64)) * 64;
    int w8 = tid >> 6, lane = tid & 63;
    int wr = w8 >> 1, wc = w8 & 1;
    int l31 = lane & 31, lg = lane >> 5;

    // ---- stage B = [Hd(64) | H(64) | C(80)] rows x 64 cols, split hi/lo ----
    {
        int col = lane;
        int tcol = t0 + col;
        const unsigned* hb = h_in + b * (RES * T);
        const unsigned* cb = c + b * (CIN * T);
        for (int kk = w8; kk < 52; kk += 8) {   // quad kk -> rows 4kk..4kk+3
            int k = kk * 4;
            unsigned v0, v1, v2, v3;
            if (k < 64) {
                int ts = tcol - d;
                bool ok = ts >= 0;
                v0 = ok ? hb[(k+0)*T + ts] : 0u;
                v1 = ok ? hb[(k+1)*T + ts] : 0u;
                v2 = ok ? hb[(k+2)*T + ts] : 0u;
                v3 = ok ? hb[(k+3)*T + ts] : 0u;
            } else if (k < 128) {
                v0 = hb[(k-64)*T + tcol];
                v1 = hb[(k-63)*T + tcol];
                v2 = hb[(k-62)*T + tcol];
                v3 = hb[(k-61)*T + tcol];
            } else {
                v0 = cb[(k-128)*T + tcol];
                v1 = cb[(k-127)*T + tcol];
                v2 = cb[(k-126)*T + tcol];
                v3 = cb[(k-125)*T + tcol];
            }
            uint2 whi = make_uint2((v0 & 0xffffu) | (v1 << 16),
                                   (v2 & 0xffffu) | (v3 << 16));
            uint2 wlo = make_uint2((v0 >> 16) | (v1 & 0xffff0000u),
                                   (v2 >> 16) | (v3 & 0xffff0000u));
            int off = ((k >> 4)*2 + (col >> 5))*512 + ((col & 31) + (((k >> 3) & 1) << 5))*8 + (k & 7);
            *(uint2*)(Bh + off) = whi;
            *(uint2*)(Bl + off) = wlo;
        }
    }
    __syncthreads();

    const unsigned short* wA = wp16 + l * L_U16;

    // ---- gate GEMM: this wave: packed rows 32wr..+31, cols 32wc..+31, K=208 ----
    f32x16 acc;
#pragma unroll
    for (int i = 0; i < 16; ++i) acc[i] = 0.f;
    {
        const bf16x8* BhF = (const bf16x8*)Bh;
        const bf16x8* BlF = (const bf16x8*)Bl;
        const unsigned short* aG = wA + (wr*13*64 + lane)*8;
#pragma unroll
        for (int kc = 0; kc < 13; ++kc) {
            bf16x8 ah = *(const bf16x8*)(aG + kc*512);
            bf16x8 al = *(const bf16x8*)(aG + AHI_SZ + kc*512);
            bf16x8 bh = BhF[(kc*2 + wc)*64 + lane];
            bf16x8 bl = BlF[(kc*2 + wc)*64 + lane];
            acc = __builtin_amdgcn_mfma_f32_32x32x16_bf16(ah, bh, acc, 0, 0, 0);
            acc = __builtin_amdgcn_mfma_f32_32x32x16_bf16(ah, bl, acc, 0, 0, 0);
            acc = __builtin_amdgcn_mfma_f32_32x32x16_bf16(al, bh, acc, 0, 0, 0);
        }
    }

    // ---- gating: pair (reg 2q, 2q+1) = (a,b) rows of z-row 16wr+jl, in-lane ----
    {
        const float* cbl = conv_b + l * GATE;
        unsigned* Zh32 = (unsigned*)Zh;
        unsigned* Zl32 = (unsigned*)Zl;
#pragma unroll
        for (int q = 0; q < 8; q += 2) {
            float z2[2];
#pragma unroll
            for (int s = 0; s < 2; ++s) {
                int qq = q + s;
                int jl = 4*(qq >> 1) + 2*lg + (qq & 1);
                int zr = 16*wr + jl;
                float a  = acc[2*qq]     + cbl[zr];
                float bb = acc[2*qq + 1] + cbl[64 + zr];
                a  = fminf(fmaxf(a, -15.f), 15.f);
                bb = fminf(fmaxf(bb, -30.f), 30.f);
                float e2 = __expf(2.f * a);
                float th = (e2 - 1.f) / (e2 + 1.f);
                float sg = 1.f / (1.f + __expf(-bb));
                z2[s] = th * sg;
            }
            unsigned short h0 = bf16_rtne(z2[0]);
            unsigned short h1 = bf16_rtne(z2[1]);
            unsigned short o0 = bf16_rtne(z2[0] - bf16_f(h0));
            unsigned short o1 = bf16_rtne(z2[1] - bf16_f(h1));
            int jl0 = 4*(q >> 1) + 2*lg;
            int zr = 16*wr + jl0;
            int off = ((zr >> 4)*2 + wc)*512 + (l31 + (((zr >> 3) & 1) << 5))*8 + (zr & 7);
            Zh32[off >> 1] = (unsigned)h0 | ((unsigned)h1 << 16);
            Zl32[off >> 1] = (unsigned)o0 | ((unsigned)o1 << 16);
        }
    }
    __syncthreads();

    // ---- second GEMM: this wave: A2 rows 32wr..+31, cols 32wc..+31, K=64 ----
    f32x16 s0;
#pragma unroll
    for (int i = 0; i < 16; ++i) s0[i] = 0.f;
    {
        const bf16x8* ZhF = (const bf16x8*)Zh;
        const bf16x8* ZlF = (const bf16x8*)Zl;
        const unsigned short* aG2 = wA + A2_OFF + (wr*4*64 + lane)*8;
#pragma unroll
        for (int kc = 0; kc < 4; ++kc) {
            bf16x8 ah = *(const bf16x8*)(aG2 + kc*512);
            bf16x8 al = *(const bf16x8*)(aG2 + A2SZ + kc*512);
            bf16x8 bh = ZhF[(kc*2 + wc)*64 + lane];
            bf16x8 bl = ZlF[(kc*2 + wc)*64 + lane];
            s0 = __builtin_amdgcn_mfma_f32_32x32x16_bf16(ah, bh, s0, 0, 0, 0);
            s0 = __builtin_amdgcn_mfma_f32_32x32x16_bf16(ah, bl, s0, 0, 0, 0);
            s0 = __builtin_amdgcn_mfma_f32_32x32x16_bf16(al, bh, s0, 0, 0, 0);
        }
    }

    // ---- epilogue: wr 0,1 -> skips (fp32 accumulate); wr 2,3 -> h_out ----
    int tcol0 = t0 + wc*32 + l31;
    if (wr < 2) {
        float* sp = skips + (b * SKIPC) * T + tcol0;
        const float* sbl = skip_b + l * SKIPC;
#pragma unroll
        for (int reg = 0; reg < 16; ++reg) {
            int row = 32*wr + (reg & 3) + 8*(reg >> 2) + 4*lg;
            int idx = row * T;
            float v = s0[reg] + sbl[row];
            if (!first) v += sp[idx];
            sp[idx] = v;
        }
    } else {
        unsigned* ho = h_out + b * (RES * T) + tcol0;
        const unsigned* hp = h_in + b * (RES * T) + tcol0;
        const float* obl = out_b + l * RES;
#pragma unroll
        for (int reg = 0; reg < 16; ++reg) {
            int row = 32*(wr - 2) + (reg & 3) + 8*(reg >> 2) + 4*lg;
            int idx = row * T;
            unsigned hv = hp[idx];
            float hf = bf16_f((unsigned short)(hv & 0xffffu)) +
                       bf16_f((unsigned short)(hv >> 16));
            ho[idx] = split_pack(hf + s0[reg] + obl[row]);
        }
    }
}

// VALU final stage (round-1 verified): out = l2 @ relu(l1 @ relu(skips) + b1) + b2
__global__ __launch_bounds__(256, 2)
void final_k(const float* __restrict__ skips, const float* __restrict__ l1T,
             const float* __restrict__ b1, const float* __restrict__ l2w,
             const float* __restrict__ b2, float* __restrict__ out) {
    int tid = blockIdx.x * 256 + threadIdx.x;
    int b = tid / T, t = tid - b * T;
    int sbase = (b * SKIPC) * T + t;
    float y1[64];
#pragma unroll
    for (int o = 0; o < 64; ++o) y1[o] = b1[o];
    for (int i = 0; i < 64; ++i) {
        float s = fmaxf(skips[sbase + i * T], 0.f);
        const float* w = l1T + i * 64;
#pragma unroll
        for (int o = 0; o < 64; ++o) y1[o] += w[o] * s;
    }
#pragma unroll
    for (int o = 0; o < 64; ++o) y1[o] = fmaxf(y1[o], 0.f);
    int obase = (b * OUTC) * T + t;
    for (int o2 = 0; o2 < OUTC; ++o2) {
        const float* w = l2w + o2 * 64;
        float acc = b2[o2];
#pragma unroll
        for (int i = 0; i < 64; ++i) acc += w[i] * y1[i];
        out[obase + o2 * T] = acc;
    }
}

extern "C" void kernel_launch(void* const* d_in, const int* in_sizes, int n_in,
                              void* d_out, int out_size, void* d_ws, size_t ws_size,
                              hipStream_t stream) {
    const int*   x       = (const int*)  d_in[0];
    const float* cond    = (const float*)d_in[1];
    const float* first_w = (const float*)d_in[2];
    const float* first_b = (const float*)d_in[3];
    const float* cin_w   = (const float*)d_in[4];
    const float* conv_w  = (const float*)d_in[5];
    const float* conv_b  = (const float*)d_in[6];
    const float* cond_w  = (const float*)d_in[7];
    const float* skip_w  = (const float*)d_in[8];
    const float* skip_b  = (const float*)d_in[9];
    const float* out_w   = (const float*)d_in[10];
    const float* out_b   = (const float*)d_in[11];
    const float* last1_w = (const float*)d_in[12];
    const float* last1_b = (const float*)d_in[13];
    const float* last2_w = (const float*)d_in[14];
    const float* last2_b = (const float*)d_in[15];
    float* out = (float*)d_out;

    // ws layout (round-1 verified): l1t fp32[4096] | wp16 | skips | c
    float* ws = (float*)d_ws;
    float* l1t = ws;
    unsigned short* wp16 = (unsigned short*)(ws + 4096);
    float* skips = ws + 4096 + (NLAYERS * L_U16) / 2;
    unsigned* c = (unsigned*)(skips + NB * SKIPC * T);

    // h double-buffer + cond temporaries live inside d_out (final_k overwrites all)
    unsigned* hA = (unsigned*)out;
    unsigned* hB = hA + NB * RES * T;
    float* c2 = (float*)(hB + NB * RES * T);
    float* c1 = c2 + NB * CIN * TM;

    pack_weights<<<4096, 256, 0, stream>>>(conv_w, cond_w, skip_w, out_w,
                                           last1_w, wp16, l1t);
    first_conv<<<(NB * T) / 256, 256, 0, stream>>>(x, first_w, first_b, hA);
    cond_in<<<(NB * TF + 255) / 256, 256, 0, stream>>>(cond, cin_w, c1);
    up1<<<(NB * CIN * TM) / 256, 256, 0, stream>>>(c1, c2);
    up2<<<(NB * CIN * T) / 256, 256, 0, stream>>>(c2, c);

    for (int l = 0; l < NLAYERS; ++l) {
        int d = 1 << (l % 10);
        const unsigned* h_in = (l & 1) ? hB : hA;
        unsigned*       h_out = (l & 1) ? hA : hB;
        layer_k<<<NB * (T / 64), 512, 0, stream>>>(h_in, h_out, skips, c, wp16,
                                                   conv_b, skip_b, out_b,
                                                   l, d, (l == 0) ? 1 : 0);
    }
    final_k<<<(NB * T) / 256, 256, 0, stream>>>(skips, l1t, last1_b, last2_w, last2_b, out);
}

// Round 6
// 5833.859 us; speedup vs baseline: 3.2696x; 1.0701x over previous
//
#include <hip/hip_runtime.h>

#define NB 8
#define T 32000
#define NLAYERS 30
#define RES 64
#define GATE 128
#define SKIPC 64
#define CIN 80
#define OUTC 256
#define TF 400
#define TM 4000

// ---- packed bf16 split-weight layout (u16 units, per layer) ----
#define K1 208          // 64 tap0 + 64 tap1 + 80 cond
#define AHI_SZ 26624    // 128*208
#define A2SZ   8192     // 128*64
#define A2_OFF (2*AHI_SZ)
#define L_U16  (2*AHI_SZ + 2*A2SZ)   // 69632 u16 per layer
// final-stage weights appended after the 30 layers
#define FIN_OFF (NLAYERS * L_U16)
#define L1P_SZ 4096                  // 64*64
#define L2P_SZ 16384                 // 256*64
#define WP16_TOTAL (FIN_OFF + 2*L1P_SZ + 2*L2P_SZ)

typedef __bf16 bf16x8 __attribute__((ext_vector_type(8)));
typedef float  f32x16 __attribute__((ext_vector_type(16)));

__device__ __forceinline__ unsigned short bf16_rtne(float x) {
    unsigned u = __float_as_uint(x);
    u += 0x7fffu + ((u >> 16) & 1u);
    return (unsigned short)(u >> 16);
}
__device__ __forceinline__ float bf16_f(unsigned short h) {
    return __uint_as_float(((unsigned)h) << 16);
}
__device__ __forceinline__ unsigned split_pack(float x) {
    unsigned short hi = bf16_rtne(x);
    unsigned short lo = bf16_rtne(x - bf16_f(hi));
    return (unsigned)hi | ((unsigned)lo << 16);
}

// Pack weights: split fp32 into bf16 hi/lo, permute gate rows (2o = tanh-row o,
// 2o+1 = sigmoid-row o+64), lay out in per-wave MFMA fragment order.
// Also packs last1 (64x64) and last2 (256x64) for the MFMA final stage.
__global__ void pack_weights(const float* __restrict__ conv_w,
                             const float* __restrict__ cond_w,
                             const float* __restrict__ skip_w,
                             const float* __restrict__ out_w,
                             const float* __restrict__ last1_w,
                             const float* __restrict__ last2_w,
                             unsigned short* __restrict__ wp16) {
    int e = blockIdx.x * 256 + threadIdx.x;
    const int NW = NLAYERS * 34816;          // 34816 = 128*208 + 128*64 elements/layer
    const int TOTAL = NW + L1P_SZ + L2P_SZ;
    if (e >= TOTAL) return;
    float wv;
    int dst, losz;
    if (e < NW) {
        int l = e / 34816, r = e % 34816;
        if (r < 26624) {                     // gate A
            int pr = r / K1, k = r % K1;
            int o = (pr & 1) * 64 + (pr >> 1);   // original gate row
            if (k < 64)       wv = conv_w[((l*GATE + o)*RES + k)*2 + 0];
            else if (k < 128) wv = conv_w[((l*GATE + o)*RES + (k-64))*2 + 1];
            else              wv = cond_w[(l*GATE + o)*CIN + (k-128)];
            int w = pr >> 5, r31 = pr & 31, kc = k >> 4, lg2 = (k >> 3) & 1, ee = k & 7;
            dst = l*L_U16 + ((w*13 + kc)*64 + lg2*32 + r31)*8 + ee;
            losz = AHI_SZ;
        } else {                             // A2: skip rows 0-63, res rows 64-127
            int r2 = r - 26624;
            int row = r2 >> 6, k = r2 & 63;
            wv = (row < 64) ? skip_w[(l*64 + row)*64 + k]
                            : out_w[(l*64 + (row-64))*64 + k];
            int w = row >> 5, r31 = row & 31, kc = k >> 4, lg2 = (k >> 3) & 1, ee = k & 7;
            dst = l*L_U16 + A2_OFF + ((w*4 + kc)*64 + lg2*32 + r31)*8 + ee;
            losz = A2SZ;
        }
    } else if (e < NW + L1P_SZ) {            // last1: 64x64
        int r = e - NW;
        int row = r >> 6, k = r & 63;
        wv = last1_w[row * 64 + k];
        int rw = row >> 5, kc = k >> 4;
        dst = FIN_OFF + ((rw*4 + kc)*64 + ((k>>3)&1)*32 + (row&31))*8 + (k&7);
        losz = L1P_SZ;
    } else {                                 // last2: 256x64
        int r = e - NW - L1P_SZ;
        int row = r >> 6, k = r & 63;
        wv = last2_w[row * 64 + k];
        int rw = row >> 5, kc = k >> 4;
        dst = FIN_OFF + 2*L1P_SZ + ((rw*4 + kc)*64 + ((k>>3)&1)*32 + (row&31))*8 + (k&7);
        losz = L2P_SZ;
    }
    unsigned short hi = bf16_rtne(wv);
    wp16[dst] = hi;
    wp16[dst + losz] = bf16_rtne(wv - bf16_f(hi));
}

// h[b,o,t] = split_pack(first_w[o, x[b,t]] + first_b[o])
__global__ void first_conv(const int* __restrict__ x, const float* __restrict__ fw,
                           const float* __restrict__ fb, unsigned* __restrict__ h) {
    int tid = blockIdx.x * 256 + threadIdx.x;
    int b = tid / T, t = tid - b * T;
    int idx = x[tid];
    int base = (b * RES) * T + t;
    for (int o = 0; o < RES; ++o)
        h[base + o * T] = split_pack(fw[o * OUTC + idx] + fb[o]);
}

__global__ void cond_in(const float* __restrict__ cond, const float* __restrict__ cw,
                        float* __restrict__ c1) {
    int tid = blockIdx.x * blockDim.x + threadIdx.x;
    if (tid >= NB * TF) return;
    int b = tid / TF, t = tid - b * TF;
    float in[CIN];
#pragma unroll
    for (int i = 0; i < CIN; ++i) in[i] = cond[(b * CIN + i) * TF + t];
    for (int o = 0; o < CIN; ++o) {
        float acc = 0.f;
#pragma unroll
        for (int i = 0; i < CIN; ++i) acc += cw[o * CIN + i] * in[i];
        c1[(b * CIN + o) * TF + t] = acc;
    }
}

__global__ void up1(const float* __restrict__ src, float* __restrict__ dst) {
    int tid = blockIdx.x * 256 + threadIdx.x;
    int t = tid % TM, rc = tid / TM;
    const float* s = src + rc * TF;
    float acc = 0.f;
#pragma unroll
    for (int k = -10; k <= 10; ++k) {
        int j = t + k;
        if (j >= 0 && j < TM) acc += s[j / 10];
    }
    dst[tid] = acc * (1.f / 21.f);
}

__global__ void up2(const float* __restrict__ src, unsigned* __restrict__ dst) {
    int tid = blockIdx.x * 256 + threadIdx.x;
    int t = tid % T, rc = tid / T;
    const float* s = src + rc * TM;
    float acc = 0.f;
#pragma unroll
    for (int k = -8; k <= 8; ++k) {
        int j = t + k;
        if (j >= 0 && j < T) acc += s[j >> 3];
    }
    dst[tid] = split_pack(acc * (1.f / 17.f));
}

// Fused WaveNet layer on matrix cores. One block = one (b, 64-wide t-tile).
// 8 waves: wave = (wr, wc); wr = 32-row group (0..3), wc = 32-col tile (0..1).
// (round-4 verified version, unchanged)
__global__ __launch_bounds__(512, 4)
void layer_k(const unsigned* __restrict__ h_in, unsigned* __restrict__ h_out,
             float* __restrict__ skips, const unsigned* __restrict__ c,
             const unsigned short* __restrict__ wp16,
             const float* __restrict__ conv_b, const float* __restrict__ skip_b,
             const float* __restrict__ out_b,
             int l, int d, int first) {
    // fragment-order LDS: [kc][nt][lane][8 u16]
    __shared__ __align__(16) unsigned short Bh[13*2*64*8];
    __shared__ __align__(16) unsigned short Bl[13*2*64*8];
    __shared__ __align__(16) unsigned short Zh[4*2*64*8];
    __shared__ __align__(16) unsigned short Zl[4*2*64*8];

    int tid = threadIdx.x;
    int blk = blockIdx.x;
    int b = blk / (T/64);
    int t0 = (blk % (T/64)) * 64;
    int w8 = tid >> 6, lane = tid & 63;
    int wr = w8 >> 1, wc = w8 & 1;
    int l31 = lane & 31, lg = lane >> 5;

    // ---- stage B = [Hd(64) | H(64) | C(80)] rows x 64 cols, split hi/lo ----
    {
        int col = lane;
        int tcol = t0 + col;
        const unsigned* hb = h_in + b * (RES * T);
        const unsigned* cb = c + b * (CIN * T);
        for (int kk = w8; kk < 52; kk += 8) {   // quad kk -> rows 4kk..4kk+3
            int k = kk * 4;
            unsigned v0, v1, v2, v3;
            if (k < 64) {
                int ts = tcol - d;
                bool ok = ts >= 0;
                v0 = ok ? hb[(k+0)*T + ts] : 0u;
                v1 = ok ? hb[(k+1)*T + ts] : 0u;
                v2 = ok ? hb[(k+2)*T + ts] : 0u;
                v3 = ok ? hb[(k+3)*T + ts] : 0u;
            } else if (k < 128) {
                v0 = hb[(k-64)*T + tcol];
                v1 = hb[(k-63)*T + tcol];
                v2 = hb[(k-62)*T + tcol];
                v3 = hb[(k-61)*T + tcol];
            } else {
                v0 = cb[(k-128)*T + tcol];
                v1 = cb[(k-127)*T + tcol];
                v2 = cb[(k-126)*T + tcol];
                v3 = cb[(k-125)*T + tcol];
            }
            uint2 whi = make_uint2((v0 & 0xffffu) | (v1 << 16),
                                   (v2 & 0xffffu) | (v3 << 16));
            uint2 wlo = make_uint2((v0 >> 16) | (v1 & 0xffff0000u),
                                   (v2 >> 16) | (v3 & 0xffff0000u));
            int off = ((k >> 4)*2 + (col >> 5))*512 + ((col & 31) + (((k >> 3) & 1) << 5))*8 + (k & 7);
            *(uint2*)(Bh + off) = whi;
            *(uint2*)(Bl + off) = wlo;
        }
    }
    __syncthreads();

    const unsigned short* wA = wp16 + l * L_U16;

    // ---- gate GEMM: this wave: packed rows 32wr..+31, cols 32wc..+31, K=208 ----
    f32x16 acc;
#pragma unroll
    for (int i = 0; i < 16; ++i) acc[i] = 0.f;
    {
        const bf16x8* BhF = (const bf16x8*)Bh;
        const bf16x8* BlF = (const bf16x8*)Bl;
        const unsigned short* aG = wA + (wr*13*64 + lane)*8;
#pragma unroll
        for (int kc = 0; kc < 13; ++kc) {
            bf16x8 ah = *(const bf16x8*)(aG + kc*512);
            bf16x8 al = *(const bf16x8*)(aG + AHI_SZ + kc*512);
            bf16x8 bh = BhF[(kc*2 + wc)*64 + lane];
            bf16x8 bl = BlF[(kc*2 + wc)*64 + lane];
            acc = __builtin_amdgcn_mfma_f32_32x32x16_bf16(ah, bh, acc, 0, 0, 0);
            acc = __builtin_amdgcn_mfma_f32_32x32x16_bf16(ah, bl, acc, 0, 0, 0);
            acc = __builtin_amdgcn_mfma_f32_32x32x16_bf16(al, bh, acc, 0, 0, 0);
        }
    }

    // ---- gating: pair (reg 2q, 2q+1) = (a,b) rows of z-row 16wr+jl, in-lane ----
    {
        const float* cbl = conv_b + l * GATE;
        unsigned* Zh32 = (unsigned*)Zh;
        unsigned* Zl32 = (unsigned*)Zl;
#pragma unroll
        for (int q = 0; q < 8; q += 2) {
            float z2[2];
#pragma unroll
            for (int s = 0; s < 2; ++s) {
                int qq = q + s;
                int jl = 4*(qq >> 1) + 2*lg + (qq & 1);
                int zr = 16*wr + jl;
                float a  = acc[2*qq]     + cbl[zr];
                float bb = acc[2*qq + 1] + cbl[64 + zr];
                a  = fminf(fmaxf(a, -15.f), 15.f);
                bb = fminf(fmaxf(bb, -30.f), 30.f);
                float e2 = __expf(2.f * a);
                float th = (e2 - 1.f) / (e2 + 1.f);
                float sg = 1.f / (1.f + __expf(-bb));
                z2[s] = th * sg;
            }
            unsigned short h0 = bf16_rtne(z2[0]);
            unsigned short h1 = bf16_rtne(z2[1]);
            unsigned short o0 = bf16_rtne(z2[0] - bf16_f(h0));
            unsigned short o1 = bf16_rtne(z2[1] - bf16_f(h1));
            int jl0 = 4*(q >> 1) + 2*lg;
            int zr = 16*wr + jl0;
            int off = ((zr >> 4)*2 + wc)*512 + (l31 + (((zr >> 3) & 1) << 5))*8 + (zr & 7);
            Zh32[off >> 1] = (unsigned)h0 | ((unsigned)h1 << 16);
            Zl32[off >> 1] = (unsigned)o0 | ((unsigned)o1 << 16);
        }
    }
    __syncthreads();

    // ---- second GEMM: this wave: A2 rows 32wr..+31, cols 32wc..+31, K=64 ----
    f32x16 s0;
#pragma unroll
    for (int i = 0; i < 16; ++i) s0[i] = 0.f;
    {
        const bf16x8* ZhF = (const bf16x8*)Zh;
        const bf16x8* ZlF = (const bf16x8*)Zl;
        const unsigned short* aG2 = wA + A2_OFF + (wr*4*64 + lane)*8;
#pragma unroll
        for (int kc = 0; kc < 4; ++kc) {
            bf16x8 ah = *(const bf16x8*)(aG2 + kc*512);
            bf16x8 al = *(const bf16x8*)(aG2 + A2SZ + kc*512);
            bf16x8 bh = ZhF[(kc*2 + wc)*64 + lane];
            bf16x8 bl = ZlF[(kc*2 + wc)*64 + lane];
            s0 = __builtin_amdgcn_mfma_f32_32x32x16_bf16(ah, bh, s0, 0, 0, 0);
            s0 = __builtin_amdgcn_mfma_f32_32x32x16_bf16(ah, bl, s0, 0, 0, 0);
            s0 = __builtin_amdgcn_mfma_f32_32x32x16_bf16(al, bh, s0, 0, 0, 0);
        }
    }

    // ---- epilogue: wr 0,1 -> skips (fp32 accumulate); wr 2,3 -> h_out ----
    int tcol0 = t0 + wc*32 + l31;
    if (wr < 2) {
        float* sp = skips + (b * SKIPC) * T + tcol0;
        const float* sbl = skip_b + l * SKIPC;
#pragma unroll
        for (int reg = 0; reg < 16; ++reg) {
            int row = 32*wr + (reg & 3) + 8*(reg >> 2) + 4*lg;
            int idx = row * T;
            float v = s0[reg] + sbl[row];
            if (!first) v += sp[idx];
            sp[idx] = v;
        }
    } else {
        unsigned* ho = h_out + b * (RES * T) + tcol0;
        const unsigned* hp = h_in + b * (RES * T) + tcol0;
        const float* obl = out_b + l * RES;
#pragma unroll
        for (int reg = 0; reg < 16; ++reg) {
            int row = 32*(wr - 2) + (reg & 3) + 8*(reg >> 2) + 4*lg;
            int idx = row * T;
            unsigned hv = hp[idx];
            float hf = bf16_f((unsigned short)(hv & 0xffffu)) +
                       bf16_f((unsigned short)(hv >> 16));
            ho[idx] = split_pack(hf + s0[reg] + obl[row]);
        }
    }
}

__device__ __forceinline__ void store_block(float* __restrict__ op,
                                            const float* __restrict__ b2,
                                            const f32x16& S, int rowb, int ntc, int lg) {
#pragma unroll
    for (int reg = 0; reg < 16; ++reg) {
        int row = rowb + (reg & 3) + 8*(reg >> 2) + 4*lg;
        op[row * T + ntc*32] = S[reg] + b2[row];
    }
}

// MFMA final stage: out = l2 @ relu(l1 @ relu(skips) + b1) + b2
// One block = one (b, 64-wide t-tile) -> grid MUST be NB*(T/64).
__global__ __launch_bounds__(256, 2)
void final_k(const float* __restrict__ skips, const unsigned short* __restrict__ wp16,
             const float* __restrict__ b1, const float* __restrict__ b2,
             float* __restrict__ out) {
    __shared__ __align__(16) unsigned short Sh[4*2*64*8];
    __shared__ __align__(16) unsigned short Sl[4*2*64*8];
    __shared__ __align__(16) unsigned short Yh[4*2*64*8];
    __shared__ __align__(16) unsigned short Yl[4*2*64*8];
    int tid = threadIdx.x, blk = blockIdx.x;
    int b = blk / (T/64), t0 = (blk % (T/64)) * 64;
    int w = tid >> 6, lane = tid & 63;
    int l31 = lane & 31, lg = lane >> 5;

    // stage relu(skips): wave w rows 16w..16w+15, col = lane
    {
        const float* sp = skips + (b * SKIPC) * T + t0 + lane;
        unsigned* Sh32 = (unsigned*)Sh;
        unsigned* Sl32 = (unsigned*)Sl;
#pragma unroll
        for (int kk = 0; kk < 16; kk += 2) {
            int k = w*16 + kk;
            float v0 = fmaxf(sp[k*T], 0.f);
            float v1 = fmaxf(sp[(k+1)*T], 0.f);
            unsigned p0 = split_pack(v0), p1 = split_pack(v1);
            int off = ((k>>4)*2 + (lane>>5))*512 + ((lane&31) + (((k>>3)&1)<<5))*8 + (k&7);
            Sh32[off >> 1] = (p0 & 0xffffu) | (p1 << 16);
            Sl32[off >> 1] = (p0 >> 16) | (p1 & 0xffff0000u);
        }
    }
    __syncthreads();

    // GEMM1 (64x64, K=64): wave w -> rows 32*(w&1), cols 32*(w>>1)
    int rw = w & 1, nt1 = w >> 1;
    f32x16 y;
#pragma unroll
    for (int i = 0; i < 16; ++i) y[i] = 0.f;
    {
        const bf16x8* ShF = (const bf16x8*)Sh;
        const bf16x8* SlF = (const bf16x8*)Sl;
        const unsigned short* aG = wp16 + FIN_OFF + (rw*4*64 + lane)*8;
#pragma unroll
        for (int kc = 0; kc < 4; ++kc) {
            bf16x8 ah = *(const bf16x8*)(aG + kc*512);
            bf16x8 al = *(const bf16x8*)(aG + L1P_SZ + kc*512);
            bf16x8 bh = ShF[(kc*2 + nt1)*64 + lane];
            bf16x8 bl = SlF[(kc*2 + nt1)*64 + lane];
            y = __builtin_amdgcn_mfma_f32_32x32x16_bf16(ah, bh, y, 0, 0, 0);
            y = __builtin_amdgcn_mfma_f32_32x32x16_bf16(ah, bl, y, 0, 0, 0);
            y = __builtin_amdgcn_mfma_f32_32x32x16_bf16(al, bh, y, 0, 0, 0);
        }
    }
    // y1 = relu(y + b1) -> Y frag layout
    {
        unsigned* Yh32 = (unsigned*)Yh;
        unsigned* Yl32 = (unsigned*)Yl;
#pragma unroll
        for (int reg = 0; reg < 16; reg += 2) {
            int row0 = 32*rw + (reg & 3) + 8*(reg >> 2) + 4*lg;
            float v0 = fmaxf(y[reg]     + b1[row0],     0.f);
            float v1 = fmaxf(y[reg + 1] + b1[row0 + 1], 0.f);
            unsigned p0 = split_pack(v0), p1 = split_pack(v1);
            int off = ((row0>>4)*2 + nt1)*512 + (l31 + (((row0>>3)&1)<<5))*8 + (row0&7);
            Yh32[off >> 1] = (p0 & 0xffffu) | (p1 << 16);
            Yl32[off >> 1] = (p0 >> 16) | (p1 & 0xffff0000u);
        }
    }
    __syncthreads();

    // GEMM2 (256x64, K=64): wave w -> rows 64w..64w+63 (row-blocks 2w, 2w+1)
    f32x16 o00, o01, o10, o11;
#pragma unroll
    for (int i = 0; i < 16; ++i) { o00[i] = 0.f; o01[i] = 0.f; o10[i] = 0.f; o11[i] = 0.f; }
    {
        const bf16x8* YhF = (const bf16x8*)Yh;
        const bf16x8* YlF = (const bf16x8*)Yl;
        const unsigned short* aG2 = wp16 + FIN_OFF + 2*L1P_SZ;
        int rb0 = 2*w, rb1 = 2*w + 1;
#pragma unroll
        for (int kc = 0; kc < 4; ++kc) {
            bf16x8 a0h = *(const bf16x8*)(aG2 + ((rb0*4 + kc)*64 + lane)*8);
            bf16x8 a0l = *(const bf16x8*)(aG2 + L2P_SZ + ((rb0*4 + kc)*64 + lane)*8);
            bf16x8 a1h = *(const bf16x8*)(aG2 + ((rb1*4 + kc)*64 + lane)*8);
            bf16x8 a1l = *(const bf16x8*)(aG2 + L2P_SZ + ((rb1*4 + kc)*64 + lane)*8);
            bf16x8 bh0 = YhF[(kc*2 + 0)*64 + lane];
            bf16x8 bh1 = YhF[(kc*2 + 1)*64 + lane];
            bf16x8 bl0 = YlF[(kc*2 + 0)*64 + lane];
            bf16x8 bl1 = YlF[(kc*2 + 1)*64 + lane];
            o00 = __builtin_amdgcn_mfma_f32_32x32x16_bf16(a0h, bh0, o00, 0, 0, 0);
            o00 = __builtin_amdgcn_mfma_f32_32x32x16_bf16(a0h, bl0, o00, 0, 0, 0);
            o00 = __builtin_amdgcn_mfma_f32_32x32x16_bf16(a0l, bh0, o00, 0, 0, 0);
            o01 = __builtin_amdgcn_mfma_f32_32x32x16_bf16(a0h, bh1, o01, 0, 0, 0);
            o01 = __builtin_amdgcn_mfma_f32_32x32x16_bf16(a0h, bl1, o01, 0, 0, 0);
            o01 = __builtin_amdgcn_mfma_f32_32x32x16_bf16(a0l, bh1, o01, 0, 0, 0);
            o10 = __builtin_amdgcn_mfma_f32_32x32x16_bf16(a1h, bh0, o10, 0, 0, 0);
            o10 = __builtin_amdgcn_mfma_f32_32x32x16_bf16(a1h, bl0, o10, 0, 0, 0);
            o10 = __builtin_amdgcn_mfma_f32_32x32x16_bf16(a1l, bh0, o10, 0, 0, 0);
            o11 = __builtin_amdgcn_mfma_f32_32x32x16_bf16(a1h, bh1, o11, 0, 0, 0);
            o11 = __builtin_amdgcn_mfma_f32_32x32x16_bf16(a1h, bl1, o11, 0, 0, 0);
            o11 = __builtin_amdgcn_mfma_f32_32x32x16_bf16(a1l, bh1, o11, 0, 0, 0);
        }
    }
    float* op = out + (b * OUTC) * T + t0 + l31;
    store_block(op, b2, o00, 64*w,      0, lg);
    store_block(op, b2, o01, 64*w,      1, lg);
    store_block(op, b2, o10, 64*w + 32, 0, lg);
    store_block(op, b2, o11, 64*w + 32, 1, lg);
}

extern "C" void kernel_launch(void* const* d_in, const int* in_sizes, int n_in,
                              void* d_out, int out_size, void* d_ws, size_t ws_size,
                              hipStream_t stream) {
    const int*   x       = (const int*)  d_in[0];
    const float* cond    = (const float*)d_in[1];
    const float* first_w = (const float*)d_in[2];
    const float* first_b = (const float*)d_in[3];
    const float* cin_w   = (const float*)d_in[4];
    const float* conv_w  = (const float*)d_in[5];
    const float* conv_b  = (const float*)d_in[6];
    const float* cond_w  = (const float*)d_in[7];
    const float* skip_w  = (const float*)d_in[8];
    const float* skip_b  = (const float*)d_in[9];
    const float* out_w   = (const float*)d_in[10];
    const float* out_b   = (const float*)d_in[11];
    const float* last1_w = (const float*)d_in[12];
    const float* last1_b = (const float*)d_in[13];
    const float* last2_w = (const float*)d_in[14];
    const float* last2_b = (const float*)d_in[15];
    float* out = (float*)d_out;

    // ws layout: wp16 u16[WP16_TOTAL] | skips fp32 | c u32   (~152 MB)
    unsigned short* wp16 = (unsigned short*)d_ws;
    float* skips = (float*)d_ws + WP16_TOTAL / 2;
    unsigned* c = (unsigned*)(skips + NB * SKIPC * T);

    // h double-buffer + cond temporaries live inside d_out (final_k overwrites all)
    unsigned* hA = (unsigned*)out;
    unsigned* hB = hA + NB * RES * T;
    float* c2 = (float*)(hB + NB * RES * T);
    float* c1 = c2 + NB * CIN * TM;

    pack_weights<<<4160, 256, 0, stream>>>(conv_w, cond_w, skip_w, out_w,
                                           last1_w, last2_w, wp16);
    first_conv<<<(NB * T) / 256, 256, 0, stream>>>(x, first_w, first_b, hA);
    cond_in<<<(NB * TF + 255) / 256, 256, 0, stream>>>(cond, cin_w, c1);
    up1<<<(NB * CIN * TM) / 256, 256, 0, stream>>>(c1, c2);
    up2<<<(NB * CIN * T) / 256, 256, 0, stream>>>(c2, c);

    for (int l = 0; l < NLAYERS; ++l) {
        int d = 1 << (l % 10);
        const unsigned* h_in = (l & 1) ? hB : hA;
        unsigned*       h_out = (l & 1) ? hA : hB;
        layer_k<<<NB * (T / 64), 512, 0, stream>>>(h_in, h_out, skips, c, wp16,
                                                   conv_b, skip_b, out_b,
                                                   l, d, (l == 0) ? 1 : 0);
    }
    // grid = NB*(T/64): one block per 64-wide t-tile (r2/r3 failed from 1000-block launch)
    final_k<<<NB * (T / 64), 256, 0, stream>>>(skips, wp16, last1_b, last2_b, out);
}